// Round 5
// baseline (126.678 us; speedup 1.0000x reference)
//
#include <hip/hip_runtime.h>

// FactorizedEmbedding: out[m,:] = embed_vocab[x[m],:] @ embed_hidden
//   x: [16384] int, ev: [128000,128] f32, eh: [128,1024] f32, out: [16384,1024] f32
//
// Split-bf16 (truncation hi + exact-residual lo) MFMA, 3 products/elem.
// prep_all (1 launch): ev rows gathered+converted -> wsA, eh^T converted -> wsB,
//   both stage-major [s:4][row][16 u32], pre-swizzled slot gs=(k8&3)^((row>>1)&3).
// femb_main: 256x256 tile, 1024 thr / 16 waves (4x4), grid=256 = 1 block/CU
//   (no tail, single prologue), K in 4 stages of 32, dbuf LDS 128 KB,
//   pure global_load_lds staging (1 KB contiguous per wave-issue),
//   explicit s_waitcnt(0) before every barrier (round-4 race fix),
//   bid map puts the 4 blocks sharing an A-panel on one XCD (A re-reads L2-local).

using f32x4 = __attribute__((ext_vector_type(4))) float;
using i32x4 = __attribute__((ext_vector_type(4))) int;
typedef unsigned int u32;

constexpr int EMB = 128;
constexpr int HID = 1024;

// 8 fp32 -> packed bf16 hi (truncate) + bf16 lo (truncate of exact residual).
__device__ inline void cvt8(const float f[8], i32x4& hi, i32x4& lo) {
    u32 h[8], l[8];
#pragma unroll
    for (int e = 0; e < 8; ++e) {
        u32 fb = __float_as_uint(f[e]);
        u32 hb = fb & 0xFFFF0000u;
        float r = f[e] - __uint_as_float(hb);    // exact residual
        u32 lb = __float_as_uint(r) & 0xFFFF0000u;
        h[e] = hb; l[e] = lb;
    }
#pragma unroll
    for (int p = 0; p < 4; ++p) {
        hi[p] = (int)((h[2*p] >> 16) | h[2*p+1]);   // elem 2p low half, 2p+1 high
        lo[p] = (int)((l[2*p] >> 16) | l[2*p+1]);
    }
}

// Earlyclobber, untied C: D never aliases A/B (HW requirement).
__device__ inline f32x4 mfma_bf16(i32x4 a, i32x4 b, f32x4 c) {
    f32x4 d;
    asm volatile("v_mfma_f32_16x16x32_bf16 %0, %1, %2, %3"
                 : "=&v"(d) : "v"(a), "v"(b), "v"(c));
    return d;
}

__device__ inline void gload16(const u32* src, u32* ldsdst) {
    __builtin_amdgcn_global_load_lds(
        (const __attribute__((address_space(1))) u32*)src,
        (__attribute__((address_space(3))) u32*)ldsdst, 16, 0, 0);
}

// ---- prep: blocks [0, M/16) gather+convert ev rows; blocks [M/16, M/16+64) eh^T.
__global__ void prep_all(const int* __restrict__ x, const float* __restrict__ ev,
                         const float* __restrict__ eh,
                         u32* __restrict__ wsAh, u32* __restrict__ wsAl,
                         u32* __restrict__ wsBh, u32* __restrict__ wsBl, int M) {
    const int bid = blockIdx.x;
    const int evblocks = M >> 4;                     // 1024
    if (bid < evblocks) {
        const int t = bid * 256 + threadIdx.x;       // [m:M][k8:16]
        const int m = t >> 4, k8 = t & 15;
        const long id = x[m];
        const float* src = ev + id * EMB + k8 * 8;
        float f[8];
        *(float4*)(f)     = *(const float4*)(src);
        *(float4*)(f + 4) = *(const float4*)(src + 4);
        i32x4 hi, lo; cvt8(f, hi, lo);
        const int s = k8 >> 2, gs = (k8 & 3) ^ ((m >> 1) & 3);
        const long off = ((long)s * M + m) * 16 + gs * 4;
        *(i32x4*)(wsAh + off) = hi;
        *(i32x4*)(wsAl + off) = lo;
    } else {
        const int t = (bid - evblocks) * 256 + threadIdx.x;  // [n:1024][k8:16]
        const int n = t >> 4, k8 = t & 15;
        float f[8];
#pragma unroll
        for (int j = 0; j < 8; ++j) f[j] = eh[(k8 * 8 + j) * HID + n];
        i32x4 hi, lo; cvt8(f, hi, lo);
        const int s = k8 >> 2, gs = (k8 & 3) ^ ((n >> 1) & 3);
        const int off = (s * HID + n) * 16 + gs * 4;
        *(i32x4*)(wsBh + off) = hi;
        *(i32x4*)(wsBl + off) = lo;
    }
}

// ---- main: 256x256 tile, 16 waves (4x4 of 64x64), K in 4 stages of 32.
__global__ __launch_bounds__(1024, 1)
void femb_main(const u32* __restrict__ wsAh, const u32* __restrict__ wsAl,
               const u32* __restrict__ wsBh, const u32* __restrict__ wsBl,
               float* __restrict__ out, int M)
{
    __shared__ __align__(16) u32 lds[2][4][4096];    // [buf][Ah,Al,Bh,Bl][16KB]

    const int tid  = threadIdx.x;
    const int lane = tid & 63, wid = tid >> 6;
    // bid -> (mt, nt): same-mt blocks (nt=0..3) have bid ≡ mt&7 (mod 8) -> same XCD.
    const int bid = blockIdx.x;
    const int mh  = bid >> 5, r5 = bid & 31;
    const int nt  = r5 >> 3,  mt = mh * 8 + (r5 & 7);
    const long m0 = (long)mt * 256, n0 = (long)nt * 256;
    const int wm  = wid >> 2, wn = wid & 3;
    const int rl  = lane & 15, g = lane >> 4;

    f32x4 acc[4][4];
#pragma unroll
    for (int i = 0; i < 4; ++i)
#pragma unroll
        for (int j = 0; j < 4; ++j) acc[i][j] = (f32x4){0.f, 0.f, 0.f, 0.f};

    // stage s: thread t copies ws row (m0 + (t>>2)), slot (t&3): u32 src off
    //   = (s*ROWS + base)*16 + t*4 (contiguous 1 KB per wave-issue);
    //   LDS dest byte = t*16 (wave-uniform base wid*1024 + lane*16).
    auto stage = [&](int s, int buf) {
        const long ao = ((long)s * M   + m0) * 16 + tid * 4;
        const long bo = ((long)s * HID + n0) * 16 + tid * 4;
        gload16(wsAh + ao, &lds[buf][0][tid * 4]);
        gload16(wsAl + ao, &lds[buf][1][tid * 4]);
        gload16(wsBh + bo, &lds[buf][2][tid * 4]);
        gload16(wsBl + bo, &lds[buf][3][tid * 4]);
    };

    auto compute = [&](int buf) {
        i32x4 bh[4], bl[4];
#pragma unroll
        for (int nf = 0; nf < 4; ++nf) {
            const int nr  = wn * 64 + nf * 16 + rl;
            const int off = nr * 16 + ((g ^ ((nr >> 1) & 3)) << 2);
            bh[nf] = *(const i32x4*)&lds[buf][2][off];
            bl[nf] = *(const i32x4*)&lds[buf][3][off];
        }
#pragma unroll
        for (int mf = 0; mf < 4; ++mf) {
            const int mr  = wm * 64 + mf * 16 + rl;
            const int off = mr * 16 + ((g ^ ((mr >> 1) & 3)) << 2);
            const i32x4 ah = *(const i32x4*)&lds[buf][0][off];
            const i32x4 al = *(const i32x4*)&lds[buf][1][off];
#pragma unroll
            for (int nf = 0; nf < 4; ++nf) {
                acc[mf][nf] = mfma_bf16(ah, bh[nf], acc[mf][nf]);
                acc[mf][nf] = mfma_bf16(ah, bl[nf], acc[mf][nf]);
                acc[mf][nf] = mfma_bf16(al, bh[nf], acc[mf][nf]);
            }
        }
    };

    stage(0, 0);
    for (int s = 0; s < 4; ++s) {
        __builtin_amdgcn_s_waitcnt(0);   // stage(s) data landed (explicit drain)
        __syncthreads();
        if (s < 3) stage(s + 1, (s + 1) & 1);   // prefetch overlaps compute(s)
        compute(s & 1);
    }

    // epilogue: C/D layout col = lane&15, row = (lane>>4)*4 + j  [m89/m91]
#pragma unroll
    for (int mf = 0; mf < 4; ++mf)
#pragma unroll
        for (int j = 0; j < 4; ++j) {
            const long row = m0 + wm * 64 + mf * 16 + g * 4 + j;
            float* dst = out + row * HID + n0 + wn * 64 + rl;
#pragma unroll
            for (int nf = 0; nf < 4; ++nf) dst[nf * 16] = acc[mf][nf][j];
        }
}

extern "C" void kernel_launch(void* const* d_in, const int* in_sizes, int n_in,
                              void* d_out, int out_size, void* d_ws, size_t ws_size,
                              hipStream_t stream) {
    const int*   x   = (const int*)d_in[0];
    const float* ev  = (const float*)d_in[1];
    const float* eh  = (const float*)d_in[2];
    float*       out = (float*)d_out;

    const int M = in_sizes[0];               // 16384

    // ws carve (u32 units): Bh 256KB | Bl 256KB | Ah 4MB | Al 4MB
    u32* wsBh = (u32*)d_ws;
    u32* wsBl = wsBh + (size_t)HID * 64;
    u32* wsAh = wsBl + (size_t)HID * 64;
    u32* wsAl = wsAh + (size_t)M * 64;
    if (ws_size < (size_t)(2 * HID * 64 + 2 * (size_t)M * 64) * 4) return;

    prep_all<<<(M >> 4) + (HID * 16 / 256), 256, 0, stream>>>(
        x, ev, eh, wsAh, wsAl, wsBh, wsBl, M);
    femb_main<<<(M / 256) * (HID / 256), 1024, 0, stream>>>(
        wsAh, wsAl, wsBh, wsBl, out, M);
}

// Round 6
// 121.379 us; speedup vs baseline: 1.0437x; 1.0437x over previous
//
#include <hip/hip_runtime.h>

// FactorizedEmbedding: out[m,:] = embed_vocab[x[m],:] @ embed_hidden
//   x: [16384] int, ev: [128000,128] f32, eh: [128,1024] f32, out: [16384,1024] f32
//
// Single fused kernel (no prep launch, no d_ws round trip).
// Split-bf16 (truncation hi + exact-residual lo) MFMA, 3 products/elem.
// 128x128 tile, 256 thr / 4 waves (2x2, 64x64 each), 2 blocks/CU.
// K in 4 stages of 32, double-buffered LDS (64 KB). Per stage region:
//   issue global loads(s+1) -> compute(s) MFMAs -> cvt+ds_write(s+1) -> barrier
// so HBM latency hides under the MFMA cluster (loads consumed only after it).
// Proven elements kept verbatim: truncation split, swizzle gs=oct^((row>>1)&3),
// earlyclobber MFMA asm, explicit s_waitcnt(0) before every barrier,
// C/D layout col=lane&15 row=(lane>>4)*4+j.

using f32x4 = __attribute__((ext_vector_type(4))) float;
using i32x4 = __attribute__((ext_vector_type(4))) int;
typedef unsigned int u32;

constexpr int EMB = 128;
constexpr int HID = 1024;

// 8 fp32 -> packed bf16 hi (truncate) + bf16 lo (truncate of exact residual).
__device__ inline void cvt8(const float f[8], i32x4& hi, i32x4& lo) {
    u32 h[8], l[8];
#pragma unroll
    for (int e = 0; e < 8; ++e) {
        u32 fb = __float_as_uint(f[e]);
        u32 hb = fb & 0xFFFF0000u;
        float r = f[e] - __uint_as_float(hb);    // exact residual
        u32 lb = __float_as_uint(r) & 0xFFFF0000u;
        h[e] = hb; l[e] = lb;
    }
#pragma unroll
    for (int p = 0; p < 4; ++p) {
        hi[p] = (int)((h[2*p] >> 16) | h[2*p+1]);   // elem 2p low half, 2p+1 high
        lo[p] = (int)((l[2*p] >> 16) | l[2*p+1]);
    }
}

// Earlyclobber, untied C: D never aliases A/B (HW requirement).
__device__ inline f32x4 mfma_bf16(i32x4 a, i32x4 b, f32x4 c) {
    f32x4 d;
    asm volatile("v_mfma_f32_16x16x32_bf16 %0, %1, %2, %3"
                 : "=&v"(d) : "v"(a), "v"(b), "v"(c));
    return d;
}

__global__ __launch_bounds__(256, 2)
void femb(const int* __restrict__ x, const float* __restrict__ ev,
          const float* __restrict__ eh, float* __restrict__ out, int mtiles)
{
    __shared__ __align__(16) u32 lds[2][4][2048];   // [buf][Ah,Al,Bh,Bl][8KB] = 64KB

    const int tid  = threadIdx.x;
    const int lane = tid & 63, wid = tid >> 6;
    const int bid  = blockIdx.x;
    const int mt   = bid % mtiles;      // same-mt blocks 128 apart -> same XCD
    const int nt   = bid / mtiles;
    const long m0  = (long)mt * 128, n0 = (long)nt * 128;
    const int wm   = wid >> 1, wn = wid & 1;
    const int rl   = lane & 15, g = lane >> 4;

    // A-gather geometry: thread covers rows r0 and r0+64, k-octet aoct of stage.
    const int r0 = tid >> 2, aoct = tid & 3;
    const float* abase0 = ev + (long)x[m0 + r0]      * EMB + aoct * 8;
    const float* abase1 = ev + (long)x[m0 + 64 + r0] * EMB + aoct * 8;
    // B geometry: column n = tid&127, k-octets boct0 and boct0+2 of stage.
    const int bn = tid & 127, boct0 = tid >> 7;
    const float* bcol = eh + n0 + bn;

    float af[2][8], bf[2][8];   // staged global data (static indexing only)

    auto loads = [&](int s) {
        const int k0 = s * 32;
#pragma unroll
        for (int h = 0; h < 2; ++h) {
            const float* src = (h ? abase1 : abase0) + k0;
            *(float4*)(&af[h][0]) = *(const float4*)(src);
            *(float4*)(&af[h][4]) = *(const float4*)(src + 4);
        }
#pragma unroll
        for (int h = 0; h < 2; ++h) {
            const int ko = k0 + (boct0 + 2 * h) * 8;
#pragma unroll
            for (int j = 0; j < 8; ++j)
                bf[h][j] = bcol[(long)(ko + j) * HID];   // coalesced across lanes
        }
    };

    auto cvtwrite = [&](int buf) {
#pragma unroll
        for (int h = 0; h < 2; ++h) {
            i32x4 hi, lo; cvt8(af[h], hi, lo);
            const int r  = r0 + h * 64;
            const int gs = aoct ^ ((r >> 1) & 3);
            *(i32x4*)&lds[buf][0][r * 16 + gs * 4] = hi;
            *(i32x4*)&lds[buf][1][r * 16 + gs * 4] = lo;
        }
#pragma unroll
        for (int h = 0; h < 2; ++h) {
            i32x4 hi, lo; cvt8(bf[h], hi, lo);
            const int o  = boct0 + 2 * h;
            const int gs = o ^ ((bn >> 1) & 3);
            *(i32x4*)&lds[buf][2][bn * 16 + gs * 4] = hi;
            *(i32x4*)&lds[buf][3][bn * 16 + gs * 4] = lo;
        }
    };

    f32x4 acc[4][4];
#pragma unroll
    for (int i = 0; i < 4; ++i)
#pragma unroll
        for (int j = 0; j < 4; ++j) acc[i][j] = (f32x4){0.f, 0.f, 0.f, 0.f};

    auto compute = [&](int buf) {
        i32x4 bh[4], bl[4];
#pragma unroll
        for (int nf = 0; nf < 4; ++nf) {
            const int nr  = wn * 64 + nf * 16 + rl;
            const int off = nr * 16 + ((g ^ ((nr >> 1) & 3)) << 2);
            bh[nf] = *(const i32x4*)&lds[buf][2][off];
            bl[nf] = *(const i32x4*)&lds[buf][3][off];
        }
#pragma unroll
        for (int mf = 0; mf < 4; ++mf) {
            const int mr  = wm * 64 + mf * 16 + rl;
            const int off = mr * 16 + ((g ^ ((mr >> 1) & 3)) << 2);
            const i32x4 ah = *(const i32x4*)&lds[buf][0][off];
            const i32x4 al = *(const i32x4*)&lds[buf][1][off];
#pragma unroll
            for (int nf = 0; nf < 4; ++nf) {
                acc[mf][nf] = mfma_bf16(ah, bh[nf], acc[mf][nf]);
                acc[mf][nf] = mfma_bf16(ah, bl[nf], acc[mf][nf]);
                acc[mf][nf] = mfma_bf16(al, bh[nf], acc[mf][nf]);
            }
        }
    };

    // prologue: stage 0 into buf 0
    loads(0);
    cvtwrite(0);
    __builtin_amdgcn_s_waitcnt(0);
    __syncthreads();

#pragma unroll
    for (int s = 0; s < 4; ++s) {
        if (s < 3) loads(s + 1);        // issue early: latency hides under MFMAs
        compute(s & 1);
        if (s < 3) cvtwrite((s + 1) & 1);  // consume loads late, write other buf
        __builtin_amdgcn_s_waitcnt(0);  // writes (and stragglers) drained
        __syncthreads();
    }

    // epilogue: C/D layout col = lane&15, row = (lane>>4)*4 + j  [m89/m91]
#pragma unroll
    for (int mf = 0; mf < 4; ++mf)
#pragma unroll
        for (int j = 0; j < 4; ++j) {
            const long row = m0 + wm * 64 + mf * 16 + g * 4 + j;
            float* dst = out + row * HID + n0 + wn * 64 + rl;
#pragma unroll
            for (int nf = 0; nf < 4; ++nf) dst[nf * 16] = acc[mf][nf][j];
        }
}

extern "C" void kernel_launch(void* const* d_in, const int* in_sizes, int n_in,
                              void* d_out, int out_size, void* d_ws, size_t ws_size,
                              hipStream_t stream) {
    const int*   x   = (const int*)d_in[0];
    const float* ev  = (const float*)d_in[1];
    const float* eh  = (const float*)d_in[2];
    float*       out = (float*)d_out;

    const int M      = in_sizes[0];          // 16384
    const int mtiles = M / 128;              // 128

    femb<<<mtiles * (HID / 128), 256, 0, stream>>>(x, ev, eh, out, mtiles);
}

// Round 7
// 120.499 us; speedup vs baseline: 1.0513x; 1.0073x over previous
//
#include <hip/hip_runtime.h>

// FactorizedEmbedding: out[m,:] = embed_vocab[x[m],:] @ embed_hidden
//   x: [16384] int, ev: [128000,128] f32, eh: [128,1024] f32, out: [16384,1024] f32
//
// Single fused kernel. Split-bf16 (truncation hi + exact-residual lo) MFMA,
// 3 products/elem. 128x128 tile, 256 thr / 4 waves (2x2, 64x64 each).
// R7 change vs R6: mono-buffered 32 KB LDS -> 4 blocks/CU (4 waves/SIMD,
// all 1024 blocks resident in ONE round; TLP replaces dbuf ILP). K in 4
// stages of 32, 2 barriers/stage (WAR + ready). cvt8 packs via v_perm_b32
// (24 VALU/8elem vs 40) -- numerics bit-identical to R6 (absmax must be 0.25).
// Proven verbatim: swizzle gs=oct^((row>>1)&3), earlyclobber MFMA asm,
// explicit s_waitcnt(0) before barriers, C/D layout col=lane&15 row=g*4+j.

using f32x4 = __attribute__((ext_vector_type(4))) float;
using i32x4 = __attribute__((ext_vector_type(4))) int;
typedef unsigned int u32;

constexpr int EMB = 128;
constexpr int HID = 1024;

// 8 fp32 -> packed bf16 hi (truncate) + bf16 lo (truncate of exact residual).
// hi pair-pack = bytes {f0.b2,f0.b3,f1.b2,f1.b3} via v_perm_b32 (no mask/shift).
__device__ inline void cvt8(const float f[8], i32x4& hi, i32x4& lo) {
    u32 rb[8];
#pragma unroll
    for (int e = 0; e < 8; ++e) {
        u32 fb = __float_as_uint(f[e]);
        float r = f[e] - __uint_as_float(fb & 0xFFFF0000u);   // exact residual
        rb[e] = __float_as_uint(r);
    }
#pragma unroll
    for (int p = 0; p < 4; ++p) {
        hi[p] = (int)__builtin_amdgcn_perm(__float_as_uint(f[2*p+1]),
                                           __float_as_uint(f[2*p]), 0x07060302u);
        lo[p] = (int)__builtin_amdgcn_perm(rb[2*p+1], rb[2*p], 0x07060302u);
    }
}

// Earlyclobber, untied C: D never aliases A/B (HW requirement).
__device__ inline f32x4 mfma_bf16(i32x4 a, i32x4 b, f32x4 c) {
    f32x4 d;
    asm volatile("v_mfma_f32_16x16x32_bf16 %0, %1, %2, %3"
                 : "=&v"(d) : "v"(a), "v"(b), "v"(c));
    return d;
}

__global__ __launch_bounds__(256, 4)
void femb(const int* __restrict__ x, const float* __restrict__ ev,
          const float* __restrict__ eh, float* __restrict__ out, int mtiles)
{
    __shared__ __align__(16) u32 lds[4][2048];   // Ah, Al, Bh, Bl : 32 KB total

    const int tid  = threadIdx.x;
    const int lane = tid & 63, wid = tid >> 6;
    const int bid  = blockIdx.x;
    const int mt   = bid % mtiles;   // A-sharing blocks: bid ≡ mt (mod 8) -> same XCD
    const int nt   = bid / mtiles;
    const long m0  = (long)mt * 128, n0 = (long)nt * 128;
    const int wm   = wid >> 1, wn = wid & 1;
    const int rl   = lane & 15, g = lane >> 4;

    // A-gather geometry: thread covers rows r0, r0+64; k-octet aoct of the stage.
    const int r0 = tid >> 2, aoct = tid & 3;
    const float* abase0 = ev + (long)x[m0 + r0]      * EMB + aoct * 8;
    const float* abase1 = ev + (long)x[m0 + 64 + r0] * EMB + aoct * 8;
    // B geometry: column n = tid&127; k-octets boct0, boct0+2 of the stage.
    const int bn = tid & 127, boct0 = tid >> 7;
    const float* bcol = eh + n0 + bn;

    f32x4 acc[4][4];
#pragma unroll
    for (int i = 0; i < 4; ++i)
#pragma unroll
        for (int j = 0; j < 4; ++j) acc[i][j] = (f32x4){0.f, 0.f, 0.f, 0.f};

    auto stagewrite = [&](int s) {
        const int k0 = s * 32;
#pragma unroll
        for (int h = 0; h < 2; ++h) {           // A rows r0, r0+64
            float f[8];
            const float* src = (h ? abase1 : abase0) + k0;
            *(float4*)(&f[0]) = *(const float4*)(src);
            *(float4*)(&f[4]) = *(const float4*)(src + 4);
            i32x4 hi, lo; cvt8(f, hi, lo);
            const int r  = r0 + h * 64;
            const int gs = aoct ^ ((r >> 1) & 3);
            *(i32x4*)&lds[0][r * 16 + gs * 4] = hi;
            *(i32x4*)&lds[1][r * 16 + gs * 4] = lo;
        }
#pragma unroll
        for (int h = 0; h < 2; ++h) {           // B k-octets boct0, boct0+2
            const int o  = boct0 + 2 * h;
            const int ko = k0 + o * 8;
            float f[8];
#pragma unroll
            for (int j = 0; j < 8; ++j)
                f[j] = bcol[(long)(ko + j) * HID];    // coalesced across lanes
            i32x4 hi, lo; cvt8(f, hi, lo);
            const int gs = o ^ ((bn >> 1) & 3);
            *(i32x4*)&lds[2][bn * 16 + gs * 4] = hi;
            *(i32x4*)&lds[3][bn * 16 + gs * 4] = lo;
        }
    };

    auto compute = [&]() {
        i32x4 bh[4], bl[4];
#pragma unroll
        for (int nf = 0; nf < 4; ++nf) {
            const int nr  = wn * 64 + nf * 16 + rl;
            const int off = nr * 16 + ((g ^ ((nr >> 1) & 3)) << 2);
            bh[nf] = *(const i32x4*)&lds[2][off];
            bl[nf] = *(const i32x4*)&lds[3][off];
        }
#pragma unroll
        for (int mf = 0; mf < 4; ++mf) {
            const int mr  = wm * 64 + mf * 16 + rl;
            const int off = mr * 16 + ((g ^ ((mr >> 1) & 3)) << 2);
            const i32x4 ah = *(const i32x4*)&lds[0][off];
            const i32x4 al = *(const i32x4*)&lds[1][off];
#pragma unroll
            for (int nf = 0; nf < 4; ++nf) {
                acc[mf][nf] = mfma_bf16(ah, bh[nf], acc[mf][nf]);
                acc[mf][nf] = mfma_bf16(ah, bl[nf], acc[mf][nf]);
                acc[mf][nf] = mfma_bf16(al, bh[nf], acc[mf][nf]);
            }
        }
    };

#pragma unroll 1
    for (int s = 0; s < 4; ++s) {
        if (s) __syncthreads();              // WAR: all waves done compute(s-1)
        stagewrite(s);
        __builtin_amdgcn_s_waitcnt(0);       // ds_writes drained before barrier
        __syncthreads();
        compute();
    }

    // epilogue: C/D layout col = lane&15, row = (lane>>4)*4 + j  [m89/m91]
#pragma unroll
    for (int mf = 0; mf < 4; ++mf)
#pragma unroll
        for (int j = 0; j < 4; ++j) {
            const long row = m0 + wm * 64 + mf * 16 + g * 4 + j;
            float* dst = out + row * HID + n0 + wn * 64 + rl;
#pragma unroll
            for (int nf = 0; nf < 4; ++nf) dst[nf * 16] = acc[mf][nf][j];
        }
}

extern "C" void kernel_launch(void* const* d_in, const int* in_sizes, int n_in,
                              void* d_out, int out_size, void* d_ws, size_t ws_size,
                              hipStream_t stream) {
    const int*   x   = (const int*)d_in[0];
    const float* ev  = (const float*)d_in[1];
    const float* eh  = (const float*)d_in[2];
    float*       out = (float*)d_out;

    const int M      = in_sizes[0];          // 16384
    const int mtiles = M / 128;              // 128

    femb<<<mtiles * (HID / 128), 256, 0, stream>>>(x, ev, eh, out, mtiles);
}